// Round 3
// baseline (694.715 us; speedup 1.0000x reference)
//
#include <hip/hip_runtime.h>
#include <hip/hip_bf16.h>
#include <cstdint>

// FM forward: out = sigmoid(x@w + w0 + 0.5*(sum_k (x@bw)_k^2 - sum_j x~_j^2 * s~_j))
// B=262144, F=512, K=64. x,bw split into bf16 hi+lo (RNE); xv via 3 MFMAs
// (hi*hi + hi*lo + lo*hi) using 32x32x16 (amortizes conv VALU + LDS B-reads over
// 32 rows/wave instead of 16). s~_j = sum_k b~_jk^2 built per block (no d_ws).
// 512-thread blocks (8 waves, 2/SIMD, <=256 VGPR: no spill risk), 4 groups of
// 256 rows; grid 256 -> 1 block/CU, prologue once per CU.

#define F_DIM 512

typedef __attribute__((ext_vector_type(8)))  short bf16x8;   // 8 bf16 = 4 VGPRs
typedef __attribute__((ext_vector_type(16))) float f32x16;

union FragU { uint32_t u[4]; uint4 q; bf16x8 v; };

// pack 2 floats -> 2 bf16 (RNE), low16 = a, high16 = b (v_cvt_pk_bf16_f32)
__device__ __forceinline__ uint32_t pk_bf16(float a, float b) {
    __hip_bfloat162 h = __float22bfloat162_rn(float2{a, b});
    union { __hip_bfloat162 h2; uint32_t u; } cv; cv.h2 = h;
    return cv.u;
}

// split one float into hi/lo bf16 bit patterns + reconstructed x~ = hi+lo
__device__ __forceinline__ void split1(float fv, uint32_t& th, uint32_t& tl, float& xt) {
    uint32_t hp = pk_bf16(fv, fv);
    th = hp & 0xFFFFu;
    float fh = __uint_as_float(hp << 16);
    float r  = fv - fh;                       // exact in fp32
    uint32_t lp = pk_bf16(r, r);
    tl = lp & 0xFFFFu;
    float fl = __uint_as_float(lp << 16);
    xt = fh + fl;
}

// Convert 8 fp32 x-values into hi/lo bf16 A-fragments; accumulate lin & tt terms.
__device__ __forceinline__ void conv8(const float4& A, const float4& Bv,
                                      const float4& wv0, const float4& wv1,
                                      const float4& sv0, const float4& sv1,
                                      FragU& H, FragU& L, float& lin, float& tt) {
    float f[8]  = {A.x, A.y, A.z, A.w, Bv.x, Bv.y, Bv.z, Bv.w};
    float wv[8] = {wv0.x, wv0.y, wv0.z, wv0.w, wv1.x, wv1.y, wv1.z, wv1.w};
    float sv[8] = {sv0.x, sv0.y, sv0.z, sv0.w, sv1.x, sv1.y, sv1.z, sv1.w};
    #pragma unroll
    for (int i = 0; i < 4; ++i) {
        float f0 = f[2 * i], f1 = f[2 * i + 1];
        uint32_t hp = pk_bf16(f0, f1);
        H.u[i] = hp;
        float fh0 = __uint_as_float(hp << 16);
        float fh1 = __uint_as_float(hp & 0xFFFF0000u);
        float r0 = f0 - fh0, r1 = f1 - fh1;
        uint32_t lp = pk_bf16(r0, r1);
        L.u[i] = lp;
        float fl0 = __uint_as_float(lp << 16);
        float fl1 = __uint_as_float(lp & 0xFFFF0000u);
        float xt0 = fh0 + fl0, xt1 = fh1 + fl1;
        tt  = fmaf(xt0 * xt0, sv[2 * i],     tt);
        tt  = fmaf(xt1 * xt1, sv[2 * i + 1], tt);
        lin = fmaf(f0, wv[2 * i],     lin);
        lin = fmaf(f1, wv[2 * i + 1], lin);
    }
}

// 512 threads = 8 waves = 2 waves/SIMD, 1 block/CU (136KB LDS).
// Wave: 32 rows/group via 32x32x16 MFMA; 4 groups -> 1024 rows/block; grid 256.
__global__ __launch_bounds__(512, 2) void fm_main(
    const float* __restrict__ x, const float* __restrict__ w0p,
    const float* __restrict__ w, const float* __restrict__ bw,
    float* __restrict__ out)
{
    extern __shared__ unsigned char smem_raw[];
    uint4* lds_b = (uint4*)smem_raw;                 // [0,4096)=hi frags, [4096,8192)=lo
    float* lds_w = (float*)(smem_raw + 131072);      // 512 f32
    float* lds_s = lds_w + 512;                      // 512 f32
    float* lds_e = lds_s + 512;                      // 8 waves * 32 f32 (epilogue xfer)

    // ---- Prologue: pack bw into 32x32x16 B-fragment layout ----
    // frag t = (kc*2+nt)*64 + L ; lane L holds B[k=kc*16+(L>>5)*8+j][n=nt*32+(L&31)], j=0..7
    for (int t = threadIdx.x; t < 4096; t += 512) {
        const int Lq = t & 63, nt = (t >> 6) & 1, kc = t >> 7;   // kc 0..31
        const int n  = nt * 32 + (Lq & 31);
        const int kb = kc * 16 + ((Lq >> 5) * 8);
        uint32_t hh[8], ll[8]; float dmy;
        #pragma unroll
        for (int j = 0; j < 8; ++j)
            split1(bw[(kb + j) * 64 + n], hh[j], ll[j], dmy);
        uint4 Hq, Lo;
        Hq.x = hh[0] | (hh[1] << 16); Hq.y = hh[2] | (hh[3] << 16);
        Hq.z = hh[4] | (hh[5] << 16); Hq.w = hh[6] | (hh[7] << 16);
        Lo.x = ll[0] | (ll[1] << 16); Lo.y = ll[2] | (ll[3] << 16);
        Lo.z = ll[4] | (ll[5] << 16); Lo.w = ll[6] | (ll[7] << 16);
        lds_b[t] = Hq;
        lds_b[4096 + t] = Lo;
    }
    // s~_j (consistent with MFMA operand values) and w -> LDS
    if (threadIdx.x < 512) {
        const int j = threadIdx.x;
        float s = 0.f;
        for (int k = 0; k < 64; ++k) {
            uint32_t a, b; float bt;
            split1(bw[j * 64 + k], a, b, bt);
            s = fmaf(bt, bt, s);
        }
        lds_s[j] = s;
        lds_w[j] = w[j];
    }
    __syncthreads();

    const int lane = threadIdx.x & 63;
    const int wave = threadIdx.x >> 6;     // 0..7
    const int m31  = lane & 31;            // row within wave tile
    const int half = lane >> 5;            // k-half
    const int koff = half * 8;
    const float w0v = w0p[0];

    for (int grp = 0; grp < 4; ++grp) {
        const size_t rowbase = ((size_t)blockIdx.x * 4 + grp) * 256 + (size_t)wave * 32;
        const float* p = x + (rowbase + m31) * F_DIM + koff;

        f32x16 acc[2];
        #pragma unroll
        for (int nt = 0; nt < 2; ++nt)
            #pragma unroll
            for (int r = 0; r < 16; ++r) acc[nt][r] = 0.f;
        float lin = 0.f, tt = 0.f;

        float4 c0 = *(const float4*)(p);
        float4 c1 = *(const float4*)(p + 4);

        for (int kc = 0; kc < 32; ++kc) {
            const int kn = (kc + 1) & 31;              // wrap: last prefetch harmless
            float4 n0 = *(const float4*)(p + kn * 16);
            float4 n1 = *(const float4*)(p + kn * 16 + 4);

            const int kb = kc * 16 + koff;
            const float4 wv0 = *(const float4*)(lds_w + kb);
            const float4 wv1 = *(const float4*)(lds_w + kb + 4);
            const float4 sv0 = *(const float4*)(lds_s + kb);
            const float4 sv1 = *(const float4*)(lds_s + kb + 4);

            FragU ah, al;
            conv8(c0, c1, wv0, wv1, sv0, sv1, ah, al, lin, tt);

            #pragma unroll
            for (int nt = 0; nt < 2; ++nt) {
                FragU bh, bl;
                const int fi = (kc * 2 + nt) * 64 + lane;
                bh.q = lds_b[fi];
                bl.q = lds_b[4096 + fi];
                acc[nt] = __builtin_amdgcn_mfma_f32_32x32x16_bf16(ah.v, bh.v, acc[nt], 0, 0, 0);
                acc[nt] = __builtin_amdgcn_mfma_f32_32x32x16_bf16(ah.v, bl.v, acc[nt], 0, 0, 0);
                acc[nt] = __builtin_amdgcn_mfma_f32_32x32x16_bf16(al.v, bh.v, acc[nt], 0, 0, 0);
            }
            c0 = n0; c1 = n1;
        }

        // ---- epilogue ----
        // C/D 32x32 layout (verified m74/m101): D[row=(r&3)+8*(r>>2)+4*half][col=nt*32+m31].
        float pa[16];
        #pragma unroll
        for (int r = 0; r < 16; ++r)
            pa[r] = fmaf(acc[1][r], acc[1][r], acc[0][r] * acc[0][r]);
        #pragma unroll
        for (int m = 1; m <= 16; m <<= 1) {
            #pragma unroll
            for (int r = 0; r < 16; ++r) pa[r] += __shfl_xor(pa[r], m, 64);
        }
        // lin/tt: lane covers row m31, its k-half -> combine halves
        lin += __shfl_xor(lin, 32, 64);
        tt  += __shfl_xor(tt, 32, 64);

        // stash row sums: one lane per half writes its 16 rows
        if (m31 == 0) {
            #pragma unroll
            for (int r = 0; r < 16; ++r) {
                const int row = (r & 3) + 8 * (r >> 2) + 4 * half;
                lds_e[wave * 32 + row] = pa[r];
            }
        }
        __builtin_amdgcn_s_waitcnt(0);       // LDS write->read, same wave
        float sq = lds_e[wave * 32 + m31];

        float a = lin + w0v + 0.5f * (sq - tt);
        float o = 1.0f / (1.0f + __expf(-a));
        if (lane < 32) out[rowbase + m31] = o;
        __syncthreads();   // protect lds_e reuse across groups (cheap, 8 waves)
    }
}

extern "C" void kernel_launch(void* const* d_in, const int* in_sizes, int n_in,
                              void* d_out, int out_size, void* d_ws, size_t ws_size,
                              hipStream_t stream) {
    const float* x  = (const float*)d_in[0];
    const float* w0 = (const float*)d_in[1];
    const float* w  = (const float*)d_in[2];
    const float* bw = (const float*)d_in[3];
    float* out = (float*)d_out;
    (void)d_ws; (void)ws_size;

    (void)hipFuncSetAttribute((const void*)fm_main,
                              hipFuncAttributeMaxDynamicSharedMemorySize, 137216);
    fm_main<<<256, 512, 137216, stream>>>(x, w0, w, bw, out);
}